// Round 5
// baseline (1826.568 us; speedup 1.0000x reference)
//
#include <hip/hip_runtime.h>
#include <hip/hip_bf16.h>

#define GLOBAL_AS __attribute__((address_space(1)))
#define LDS_AS    __attribute__((address_space(3)))

typedef __bf16 bf16_t;
typedef __bf16 bf16x8 __attribute__((ext_vector_type(8)));
typedef __bf16 bf16x4 __attribute__((ext_vector_type(4)));
typedef float  f32x4  __attribute__((ext_vector_type(4)));
typedef _Float16 fp16_t;

static constexpr int Ss = 14;     // seq
static constexpr int Hh = 1024;   // hidden
static constexpr int Cc = 2513;   // classes
static constexpr int NXc = 3584;  // B*S
static constexpr int Kk = 1024;   // K
static constexpr int NB = 512;    // persistent blocks (2/CU guaranteed)

__device__ __forceinline__ float sigm(float x)   { return 1.0f / (1.0f + __expf(-x)); }
__device__ __forceinline__ float tanh_f(float x) { return 2.0f / (1.0f + __expf(-2.0f * x)) - 1.0f; }

// ---------------------------------------------------------------------------
// 128x128 K=1024 tile GEMM core (m97 recipe). REMAP: A-row b*14+s -> s*256+b.
// ---------------------------------------------------------------------------
template<bool REMAP>
__device__ __forceinline__ void tile_gemm(
    const bf16_t* Abase, int arow0, const bf16_t* Bbase, int brow0,
    LDS_AS char* sA, LDS_AS char* sB,
    int tid, int mwb, int nwb, int quad, int l15, f32x4 (&acc)[4][4])
{
    for (int kb = 0; kb < Kk; kb += 64) {
#pragma unroll
        for (int it = 0; it < 4; ++it) {
            int c  = it * 256 + tid;
            int m  = c >> 3;
            int kq = (c & 7) ^ (m & 7);
            int ar = arow0 + m;
            if (REMAP) { int bb = ar / 14; int ss = ar - bb * 14; ar = ss * 256 + bb; }
            const bf16_t* ga = Abase + (size_t)ar * Kk + kb + kq * 8;
            const bf16_t* gb = Bbase + (size_t)(brow0 + m) * Kk + kb + kq * 8;
            LDS_AS char* la = sA + (size_t)(it * 256 + (tid & 192)) * 16;
            LDS_AS char* lb = sB + (size_t)(it * 256 + (tid & 192)) * 16;
            __builtin_amdgcn_global_load_lds((const GLOBAL_AS void*)ga, (LDS_AS void*)la, 16, 0, 0);
            __builtin_amdgcn_global_load_lds((const GLOBAL_AS void*)gb, (LDS_AS void*)lb, 16, 0, 0);
        }
        __syncthreads();
#pragma unroll
        for (int kt = 0; kt < 2; ++kt) {
            bf16x8 af[4], bfr[4];
            const int kq = kt * 4 + quad;
#pragma unroll
            for (int i = 0; i < 4; ++i) {
                int ml = mwb + i * 16 + l15;
                af[i]  = *(const LDS_AS bf16x8*)(sA + (size_t)(ml * 8 + (kq ^ (ml & 7))) * 16);
                int nl = nwb + i * 16 + l15;
                bfr[i] = *(const LDS_AS bf16x8*)(sB + (size_t)(nl * 8 + (kq ^ (nl & 7))) * 16);
            }
#pragma unroll
            for (int i = 0; i < 4; ++i)
#pragma unroll
                for (int j = 0; j < 4; ++j)
                    acc[i][j] = __builtin_amdgcn_mfma_f32_16x16x32_bf16(af[i], bfr[j], acc[i][j], 0, 0, 0);
        }
        __syncthreads();
    }
}

// grid barrier: release add -> relaxed poll -> agent acquire fence
__device__ __forceinline__ void gbar(unsigned* ctr, int tid)
{
    __syncthreads();
    if (tid == 0) {
        __hip_atomic_fetch_add(ctr, 1u, __ATOMIC_RELEASE, __HIP_MEMORY_SCOPE_AGENT);
        while (__hip_atomic_load(ctr, __ATOMIC_RELAXED, __HIP_MEMORY_SCOPE_AGENT) < (unsigned)NB)
            __builtin_amdgcn_s_sleep(2);
    }
    __syncthreads();
    __builtin_amdgcn_fence(__ATOMIC_ACQUIRE, "agent");
}

// ---------------------------------------------------------------------------
struct PArgs {
    const bf16_t* w_ih2;   // [8192,1024] gate-interleaved rows [roll|unroll]
    const bf16_t* w_hhr;   // [4096,1024]
    const bf16_t* w_hhu;   // [4096,1024]
    const bf16_t* x_b;     // [3584,1024] rows s*256+b
    const bf16_t* wc;      // [2560,1024] (rows >=2513 garbage, masked)
    const float*  bias2;   // [2048][4]
    bf16_t* XG2;           // [2048][3584][4]
    bf16_t* P0; bf16_t* P1;   // h ping-pong [3584][1024] bf16
    fp16_t* C0; fp16_t* C1;   // c ping-pong fp16
    const float* bc;
    float* out;            // [3584][2513]
    unsigned* bar;         // 32 counters, zeroed
};

// ---------------------------------------------------------------------------
// One persistent kernel: 16 phase-barriered recurrent steps (step 1 fused with
// xg_r[0]), XG tiles as filler in early-phase slack, classifier at the end.
// ---------------------------------------------------------------------------
__global__ __launch_bounds__(256, 2)
void rulstm_persist(PArgs p)
{
    __shared__ char smem[32768];
    LDS_AS char* sA = (LDS_AS char*)smem;
    LDS_AS char* sB = sA + 16384;

    const int tid  = threadIdx.x;
    const int lane = tid & 63;
    const int wave = tid >> 6;
    const int mwb  = (wave >> 1) * 64;
    const int nwb  = (wave & 1) * 64;
    const int quad = lane >> 4;
    const int l15  = lane & 15;
    const int bid  = blockIdx.x;

    int xg_base = 0;
    for (int k = 1; k <= 16; ++k) {
        const int a   = (k - 1 < 14) ? (k - 1) : 14;
        const int UCB = 2 * a;
        const int CB  = (k == 1) ? 2 : (UCB + ((k <= 14) ? 2 : 0));
        const int rec = 32 * CB;
        const int R   = (rec > NB) ? 2 : 1;

        for (int r = 0; r < R; ++r) {
            const int j = r * NB + bid;
            if (j < rec) {
                const int u  = j >> 6, v = j & 63;
                const int cb = 2 * u + (v & 1);
                const int rb = v >> 1;
                f32x4 acc[4][4] = {};
                if (k == 1) {
                    // fused: gates = W_ihr @ x[:,0:256] + bias_r; h0=c0=0
                    tile_gemm<false>(p.w_ih2, rb * 128, p.x_b, cb * 128,
                                     sA, sB, tid, mwb, nwb, quad, l15, acc);
#pragma unroll
                    for (int im = 0; im < 4; ++im)
#pragma unroll
                        for (int jn = 0; jn < 4; ++jn) {
                            const int rr = rb * 128 + mwb + im * 16 + quad * 4;
                            const int n  = rr >> 2;
                            const int col = cb * 128 + nwb + jn * 16 + l15;
                            f32x4 v4 = acc[im][jn];
                            f32x4 bi = *(const f32x4*)(p.bias2 + n * 4);
                            float c2 = sigm(v4[0] + bi[0]) * tanh_f(v4[2] + bi[2]);
                            float h2 = sigm(v4[3] + bi[3]) * tanh_f(c2);
                            p.C1[((size_t)col << 10) + n] = (fp16_t)c2;
                            p.P1[((size_t)col << 10) + n] = (bf16_t)h2;
                        }
                } else {
                    const bool roll = (k <= 14) && (cb >= UCB);
                    const bf16_t* A = roll ? p.w_hhr : p.w_hhu;
                    const int bcol0 = roll ? ((k - 2) * 256 + (cb - UCB) * 128) : cb * 128;
                    const bf16_t* hprev = (k & 1) ? p.P0 : p.P1;   // h[k-1]
                    const fp16_t* cprev = (k & 1) ? p.C0 : p.C1;
                    bf16_t* hw = (k & 1) ? p.P1 : p.P0;
                    fp16_t* cw = (k & 1) ? p.C1 : p.C0;
                    tile_gemm<false>(A, rb * 128, hprev, bcol0,
                                     sA, sB, tid, mwb, nwb, quad, l15, acc);
                    const bf16_t* xg = roll ? p.XG2 : (p.XG2 + (size_t)1024 * NXc * 4);
                    const int wbase = roll ? ((k - 1) * 256 + (cb - UCB) * 128) : cb * 128;
#pragma unroll
                    for (int im = 0; im < 4; ++im)
#pragma unroll
                        for (int jn = 0; jn < 4; ++jn) {
                            const int rr = rb * 128 + mwb + im * 16 + quad * 4;
                            const int n  = rr >> 2;
                            const int cl = nwb + jn * 16 + l15;
                            const int xcol = wbase + cl;   // xg col == write col
                            const int rcol = bcol0 + cl;   // c read col
                            f32x4 v4 = acc[im][jn];
                            bf16x4 xg4 = *(const bf16x4*)(xg + ((size_t)n * NXc + xcol) * 4);
                            float gi = v4[0] + (float)xg4[0];
                            float gf = v4[1] + (float)xg4[1];
                            float gg = v4[2] + (float)xg4[2];
                            float go = v4[3] + (float)xg4[3];
                            float cold = (float)cprev[((size_t)rcol << 10) + n];
                            float c2 = sigm(gf) * cold + sigm(gi) * tanh_f(gg);
                            float h2 = sigm(go) * tanh_f(c2);
                            cw[((size_t)xcol << 10) + n] = (fp16_t)c2;
                            hw[((size_t)xcol << 10) + n] = (bf16_t)h2;
                        }
                }
            } else {
                const int g = xg_base + (j - rec);
                if (g < 1728) {
                    // XG filler tile, deadline-ordered
                    int rbF, cbx;
                    if (g < 1664) {
                        const int grp = g >> 7, rr2 = g & 127;
                        if (rr2 < 64) { rbF = rr2 >> 1; cbx = 2 * (grp + 1) + (rr2 & 1); }
                        else { rbF = 32 + ((rr2 - 64) >> 1); cbx = 2 * grp + ((rr2 - 64) & 1); }
                    } else {
                        const int rr2 = g - 1664;
                        rbF = 32 + (rr2 >> 1); cbx = 26 + (rr2 & 1);
                    }
                    f32x4 acc[4][4] = {};
                    tile_gemm<false>(p.w_ih2, rbF * 128, p.x_b, cbx * 128,
                                     sA, sB, tid, mwb, nwb, quad, l15, acc);
#pragma unroll
                    for (int im = 0; im < 4; ++im)
#pragma unroll
                        for (int jn = 0; jn < 4; ++jn) {
                            const int rr = rbF * 128 + mwb + im * 16 + quad * 4;
                            const int n  = rr >> 2;
                            const int col = cbx * 128 + nwb + jn * 16 + l15;
                            f32x4 v4 = acc[im][jn];
                            f32x4 bi = *(const f32x4*)(p.bias2 + n * 4);
                            bf16x4 o;
                            o[0] = (bf16_t)(v4[0] + bi[0]); o[1] = (bf16_t)(v4[1] + bi[1]);
                            o[2] = (bf16_t)(v4[2] + bi[2]); o[3] = (bf16_t)(v4[3] + bi[3]);
                            *(bf16x4*)(p.XG2 + ((size_t)n * NXc + col) * 4) = o;
                        }
                }
            }
        }
        xg_base += R * NB - rec;
        gbar(p.bar + k, tid);
    }

    // ---------------- classifier (h[16] = P0) ----------------
    for (int r = 0; r < 2; ++r) {
        const int j = r * NB + bid;
        if (j < 560) {
            const int rb = j / 20, cbn = j % 20;
            const int row0 = rb * 128, col0 = cbn * 128;
            f32x4 acc[4][4] = {};
            tile_gemm<true>(p.P0, row0, p.wc, col0,
                            sA, sB, tid, mwb, nwb, quad, l15, acc);
#pragma unroll
            for (int im = 0; im < 4; ++im)
#pragma unroll
                for (int jn = 0; jn < 4; ++jn) {
                    const int rr  = row0 + mwb + im * 16 + quad * 4;
                    const int col = col0 + nwb + jn * 16 + l15;
                    f32x4 v4 = acc[im][jn];
                    if (col < Cc) {
                        float bi = p.bc[col];
#pragma unroll
                        for (int g2 = 0; g2 < 4; ++g2)
                            p.out[(size_t)(rr + g2) * Cc + col] = v4[g2] + bi;
                    }
                }
        }
    }
}

// ---------------------------------------------------------------------------
// Conversions
// ---------------------------------------------------------------------------
__global__ void cvt_w(const float* __restrict__ a0, const float* __restrict__ a1,
                      const float* __restrict__ a2, const float* __restrict__ a3,
                      bf16_t* __restrict__ o0, bf16_t* __restrict__ o1,
                      bf16_t* __restrict__ o2, bf16_t* __restrict__ o3)
{
    int idx = blockIdx.x * 256 + threadIdx.x;
    int mat = idx >> 20;
    int r   = (idx >> 8) & 4095;
    int k4  = (idx & 255) * 4;
    int n = r >> 2, g = r & 3;
    const float* src = mat == 0 ? a0 : mat == 1 ? a1 : mat == 2 ? a2 : a3;
    bf16_t*      dst = mat == 0 ? o0 : mat == 1 ? o1 : mat == 2 ? o2 : o3;
    f32x4 v = *(const f32x4*)(src + (size_t)(g * Hh + n) * Kk + k4);
    bf16x4 o;
    o[0] = (bf16_t)v[0]; o[1] = (bf16_t)v[1]; o[2] = (bf16_t)v[2]; o[3] = (bf16_t)v[3];
    *(bf16x4*)(dst + (size_t)r * Kk + k4) = o;
}

__global__ void cvt_bias(const float* __restrict__ bih_r, const float* __restrict__ bhh_r,
                         const float* __restrict__ bih_u, const float* __restrict__ bhh_u,
                         float* __restrict__ br, float* __restrict__ bu)
{
    int r = blockIdx.x * 256 + threadIdx.x;
    int n = r >> 2, g = r & 3;
    int ir = g * Hh + n;
    br[r] = bih_r[ir] + bhh_r[ir];
    bu[r] = bih_u[ir] + bhh_u[ir];
}

__global__ void cvt_x(const float* __restrict__ src, bf16_t* __restrict__ dst)
{
    int idx = blockIdx.x * 256 + threadIdx.x;
    int f4  = (idx & 255) * 4;
    int row = idx >> 8;
    int s = row % 14, b = row / 14;
    f32x4 v = *(const f32x4*)(src + (size_t)row * Kk + f4);
    bf16x4 o;
    o[0] = (bf16_t)v[0]; o[1] = (bf16_t)v[1]; o[2] = (bf16_t)v[2]; o[3] = (bf16_t)v[3];
    *(bf16x4*)(dst + (size_t)(s * 256 + b) * Kk + f4) = o;
}

__global__ void cast_f32_bf16(const float* __restrict__ src, bf16_t* __restrict__ dst, int n4)
{
    int i = blockIdx.x * 256 + threadIdx.x;
    if (i < n4) {
        f32x4 v = *(const f32x4*)(src + (size_t)i * 4);
        bf16x4 o;
        o[0] = (bf16_t)v[0]; o[1] = (bf16_t)v[1]; o[2] = (bf16_t)v[2]; o[3] = (bf16_t)v[3];
        *(bf16x4*)(dst + (size_t)i * 4) = o;
    }
}

// ---------------------------------------------------------------------------
extern "C" void kernel_launch(void* const* d_in, const int* in_sizes, int n_in,
                              void* d_out, int out_size, void* d_ws, size_t ws_size,
                              hipStream_t stream)
{
    const float* x_in  = (const float*)d_in[0];
    const float* Wih_r = (const float*)d_in[1];
    const float* Whh_r = (const float*)d_in[2];
    const float* bih_r = (const float*)d_in[3];
    const float* bhh_r = (const float*)d_in[4];
    const float* Wih_u = (const float*)d_in[5];
    const float* Whh_u = (const float*)d_in[6];
    const float* bih_u = (const float*)d_in[7];
    const float* bhh_u = (const float*)d_in[8];
    const float* Wc    = (const float*)d_in[9];
    const float* bc    = (const float*)d_in[10];
    float* out = (float*)d_out;

    char* ws = (char*)d_ws;
    size_t off = 0;
    auto alloc = [&](size_t bytes) -> char* {
        char* p = ws + off;
        off += (bytes + 255) & ~(size_t)255;
        return p;
    };

    const size_t SBH = (size_t)NXc * Hh;               // 3,670,016 elems
    bf16_t*   w_ih2 = (bf16_t*)alloc((size_t)8192 * Kk * 2);
    bf16_t*   w_hhr = (bf16_t*)alloc((size_t)4096 * Kk * 2);
    bf16_t*   w_hhu = (bf16_t*)alloc((size_t)4096 * Kk * 2);
    bf16_t*   wc_b  = (bf16_t*)alloc((size_t)2560 * Kk * 2);  // padded rows
    bf16_t*   x_b   = (bf16_t*)alloc((size_t)NXc * Kk * 2);
    float*    bias2 = (float*)alloc(8192 * 4);
    bf16_t*   XG2   = (bf16_t*)alloc((size_t)2048 * NXc * 4 * 2);
    bf16_t*   P0    = (bf16_t*)alloc(SBH * 2);
    bf16_t*   P1    = (bf16_t*)alloc(SBH * 2);
    fp16_t*   C0    = (fp16_t*)alloc(SBH * 2);
    fp16_t*   C1    = (fp16_t*)alloc(SBH * 2);
    unsigned* bar   = (unsigned*)alloc(32 * 4);

    hipMemsetAsync(bar, 0, 32 * 4, stream);

    cvt_w<<<16384, 256, 0, stream>>>(Wih_r, Whh_r, Wih_u, Whh_u,
                                     w_ih2, w_hhr, w_ih2 + (size_t)4096 * Kk, w_hhu);
    cvt_bias<<<16, 256, 0, stream>>>(bih_r, bhh_r, bih_u, bhh_u, bias2, bias2 + 4096);
    cvt_x<<<3584, 256, 0, stream>>>(x_in, x_b);
    cast_f32_bf16<<<(Cc * Kk / 4 + 255) / 256, 256, 0, stream>>>(Wc, wc_b, Cc * Kk / 4);

    PArgs p;
    p.w_ih2 = w_ih2;
    p.w_hhr = w_hhr;
    p.w_hhu = w_hhu;
    p.x_b   = x_b;
    p.wc    = wc_b;
    p.bias2 = bias2;
    p.XG2   = XG2;
    p.P0 = P0; p.P1 = P1;
    p.C0 = C0; p.C1 = C1;
    p.bc  = bc;
    p.out = out;
    p.bar = bar;
    rulstm_persist<<<NB, 256, 0, stream>>>(p);
}